// Round 9
// baseline (238.648 us; speedup 1.0000x reference)
//
#include <hip/hip_runtime.h>
#include <hip/hip_cooperative_groups.h>

namespace cg = cooperative_groups;

// Problem constants
#define Bc  32
#define Nc  16
#define Tc  64
#define Hc  256
#define NTc 1024   // N*T

typedef unsigned short u16;
using v8s = __attribute__((ext_vector_type(8))) short;   // 8 bf16 = 4 VGPRs (MFMA A/B frag)
using v4f = __attribute__((ext_vector_type(4))) float;   // MFMA C/D frag

// fp32 -> bf16 round-to-nearest-even (inputs finite)
static __device__ __forceinline__ u16 f2bf(float x) {
    unsigned u = __float_as_uint(x);
    unsigned r = u + 0x7fffu + ((u >> 16) & 1u);
    return (u16)(r >> 16);
}
static __device__ __forceinline__ float bf2f(u16 h) {
    return __uint_as_float(((unsigned)h) << 16);
}

// ws layout (u16 units):
//  NODEf [B][4096 frags][8]: f<2048 = node-hi frag-major, f>=2048 = node-lo
//        frag f=(nt*8+ksb)*64+lane holds node[t=nt*16+c][h=ksb*32+quad*8+j]
//  MTf   [B][2048 frags][8]: f=(ht*2+ktb)*64+lane holds M[t=ktb*32+quad*8+j][h=ht*16+c]
//  Wsum  [B][T] fp32
#define NODEF_SZ ((size_t)Bc * 4096 * 8)
#define MTF_SZ   ((size_t)Bc * 2048 * 8)

// ---------------------------------------------------------------------------
// Single cooperative kernel, 512 blocks x 256 threads, 2 blocks/CU.
//  Phase 0 (prep): block bk=(b,hc): mean over i for h-chunk hc -> MTf frags
//    (R6's measured-fast mapping); node hi/lo split spread over ALL blocks
//    (128 frags each, threads 128..255); Wsum zeroed by blocks 0..31.
//  grid.sync()
//  Phase 1 (fused, block=(b,i)): stage NODEf[b] hi+lo (64 KB) into LDS;
//    Phase A: A-frags from neigh rows w/ in-reg hi/lo split, B-frags from
//    LDS, 3 MFMAs (hh+hl+lh); softmax in C-layout regs; Wsum atomics;
//    P C->A transpose via wave-private LDS band; restage MTf (32 KB);
//    Phase B: out = P @ M from LDS.
//  grid.sync()
//  Phase 2: blocks 0..127 expand W[b,i,t] = Wsum[b,t]/16.
// Frag layouts (m89/m97-verified): A/B (m|n)=lane&15, k=quad*8+j;
//                                  C/D col=lane&15, row=quad*4+reg.
// LDS: 64 KB Bs (Ls overlays it in phase 0) + 9.2 KB Ph = 73.4 KB.
// ---------------------------------------------------------------------------
__global__ __launch_bounds__(256, 2) void mono_kernel(const float* __restrict__ neigh,
                                                      const float* __restrict__ node,
                                                      const int*   __restrict__ nbr,
                                                      u16* __restrict__ NODEf,
                                                      u16* __restrict__ MTf,
                                                      float* __restrict__ Wsum,
                                                      float* __restrict__ out,
                                                      float* __restrict__ Wout) {
    __shared__ __align__(16) u16 Bs[4096 * 8];   // 64 KB; phase 0 overlays Ls here
    __shared__ u16 Ph[64][72];

    cg::grid_group grid = cg::this_grid();

    int bk  = blockIdx.x;
    int tid = threadIdx.x;

    // ================= Phase 0: prep =================
    {
        float (*Ls)[17] = (float(*)[17])Bs;      // [64][17] fp32, 4.4 KB of Bs
        int b  = bk >> 4;
        int hc = bk & 15;
        int h0 = hc << 4;

        if (bk < 32 && tid < 64) Wsum[bk * 64 + tid] = 0.f;

        // mean over i: thread (t = tid>>2, h4 = tid&3)
        {
            int t  = tid >> 2;
            int h4 = tid & 3;
            const float4* p = (const float4*)(neigh + ((size_t)(b * Nc * Tc) + t) * Hc + h0) + h4;
            float4 a = make_float4(0.f, 0.f, 0.f, 0.f);
#pragma unroll
            for (int i = 0; i < Nc; i++) {
                float4 v = p[(size_t)i * (Tc * Hc / 4)];
                a.x += v.x; a.y += v.y; a.z += v.z; a.w += v.w;
            }
            const float r = 1.0f / 16.0f;
            Ls[t][h4 * 4 + 0] = a.x * r;
            Ls[t][h4 * 4 + 1] = a.y * r;
            Ls[t][h4 * 4 + 2] = a.z * r;
            Ls[t][h4 * 4 + 3] = a.w * r;
        }
        __syncthreads();

        if (tid < 128) {
            // MTf frags for (b, ht=hc): 128 frags
            int ktb  = tid >> 6;
            int lane = tid & 63;
            int quad = lane >> 4;
            int c    = lane & 15;
            v8s o;
#pragma unroll
            for (int j = 0; j < 8; j++)
                o[j] = (short)f2bf(Ls[ktb * 32 + quad * 8 + j][c]);
            *(v8s*)(MTf + ((size_t)b * 2048 + (hc * 2 + ktb) * 64 + lane) * 8) = o;
        } else {
            // node hi/lo split: global frag g = bk*128 + (tid-128)
            int g    = bk * 128 + (tid - 128);   // 0..65535
            int bn   = g >> 11;
            int f    = g & 2047;
            int nt   = f >> 9;
            int ksb  = (f >> 6) & 7;
            int lane = f & 63;
            int quad = lane >> 4;
            int cc   = lane & 15;
            const float* src = node + ((size_t)bn * Tc + nt * 16 + cc) * Hc + ksb * 32 + quad * 8;
            float4 f0 = *(const float4*)(src);
            float4 f1 = *(const float4*)(src + 4);
            v8s hs, ls;
            float vin[8] = {f0.x, f0.y, f0.z, f0.w, f1.x, f1.y, f1.z, f1.w};
#pragma unroll
            for (int j = 0; j < 8; j++) {
                u16 h = f2bf(vin[j]);
                hs[j] = (short)h;
                ls[j] = (short)f2bf(vin[j] - bf2f(h));
            }
            *(v8s*)(NODEf + ((size_t)bn * 4096 + f) * 8)        = hs;
            *(v8s*)(NODEf + ((size_t)bn * 4096 + 2048 + f) * 8) = ls;
        }
    }

    grid.sync();   // prep results visible grid-wide

    // ================= Phase 1: fused attention =================
    {
        int b  = bk >> 4;
        int i  = bk & 15;
        int q0 = i << 6;

        int w    = tid >> 6;
        int lane = tid & 63;
        int quad = lane >> 4;
        int c    = lane & 15;

        // neighbors_number: int64 per reference; harness may upload int32.
        // Values in [1,16] so nbr[1]==0 <=> int64 (high word of elem 0).
        int nb = (nbr[1] == 0) ? nbr[2 * b] : nbr[b];
        float rscale = rsqrtf((float)nb);

        // Stage node hi+lo frags (64 KB)
        const u16* NFb = NODEf + (size_t)b * 4096 * 8;
#pragma unroll
        for (int rep = 0; rep < 16; rep++) {
            int ch = rep * 256 + tid;
            *(uint4*)&Bs[ch * 8] = *(const uint4*)(NFb + ch * 8);
        }
        __syncthreads();

        const float* Xrow = neigh + ((size_t)(b * Nc * Tc) + q0 + w * 16 + c) * Hc;

        v4f acc[4];
#pragma unroll
        for (int nt = 0; nt < 4; nt++)
#pragma unroll
            for (int rg = 0; rg < 4; rg++) acc[nt][rg] = 0.f;

        // Phase A: K=256, 8 k-steps of 32
#pragma unroll
        for (int ksb = 0; ksb < 8; ksb++) {
            float4 f0 = *(const float4*)(Xrow + ksb * 32 + quad * 8);
            float4 f1 = *(const float4*)(Xrow + ksb * 32 + quad * 8 + 4);
            v8s ah, al;
            {
                float vin[8] = {f0.x, f0.y, f0.z, f0.w, f1.x, f1.y, f1.z, f1.w};
#pragma unroll
                for (int j = 0; j < 8; j++) {
                    u16 h = f2bf(vin[j]);
                    ah[j] = (short)h;
                    al[j] = (short)f2bf(vin[j] - bf2f(h));
                }
            }
#pragma unroll
            for (int nt = 0; nt < 4; nt++) {
                int f = (nt * 8 + ksb) * 64 + lane;
                v8s bh = *(const v8s*)&Bs[f * 8];
                v8s bl = *(const v8s*)&Bs[(f + 2048) * 8];
                acc[nt] = __builtin_amdgcn_mfma_f32_16x16x32_bf16(ah, bh, acc[nt], 0, 0, 0);
                acc[nt] = __builtin_amdgcn_mfma_f32_16x16x32_bf16(ah, bl, acc[nt], 0, 0, 0);
                acc[nt] = __builtin_amdgcn_mfma_f32_16x16x32_bf16(al, bh, acc[nt], 0, 0, 0);
            }
        }

        // Softmax over t (C-layout: col = nt*16+c, row = w*16+quad*4+rg)
#pragma unroll
        for (int nt = 0; nt < 4; nt++)
#pragma unroll
            for (int rg = 0; rg < 4; rg++) acc[nt][rg] *= rscale;

#pragma unroll
        for (int rg = 0; rg < 4; rg++) {
            float m = fmaxf(fmaxf(acc[0][rg], acc[1][rg]), fmaxf(acc[2][rg], acc[3][rg]));
#pragma unroll
            for (int d = 1; d < 16; d <<= 1) m = fmaxf(m, __shfl_xor(m, d));
            float e0 = __expf(acc[0][rg] - m);
            float e1 = __expf(acc[1][rg] - m);
            float e2 = __expf(acc[2][rg] - m);
            float e3 = __expf(acc[3][rg] - m);
            float s = e0 + e1 + e2 + e3;
#pragma unroll
            for (int d = 1; d < 16; d <<= 1) s += __shfl_xor(s, d);
            float inv = 1.0f / s;
            acc[0][rg] = e0 * inv; acc[1][rg] = e1 * inv;
            acc[2][rg] = e2 * inv; acc[3][rg] = e3 * inv;
        }

        // Column sums -> Wsum atomics (device scope, fire-and-forget)
#pragma unroll
        for (int nt = 0; nt < 4; nt++) {
            float cs = acc[nt][0] + acc[nt][1] + acc[nt][2] + acc[nt][3];
            cs += __shfl_xor(cs, 16);
            cs += __shfl_xor(cs, 32);
            if (quad == 0) atomicAdd(&Wsum[b * Tc + nt * 16 + c], cs);
        }

        // P -> wave-private LDS band (C->A transpose, intra-wave)
#pragma unroll
        for (int nt = 0; nt < 4; nt++)
#pragma unroll
            for (int rg = 0; rg < 4; rg++)
                Ph[w * 16 + quad * 4 + rg][nt * 16 + c] = f2bf(acc[nt][rg]);

        v8s pa0 = *(const v8s*)&Ph[w * 16 + c][quad * 8];
        v8s pa1 = *(const v8s*)&Ph[w * 16 + c][32 + quad * 8];

        __syncthreads();   // Phase A reads of Bs done

        // Restage MTf (32 KB) into the reused LDS region
        const u16* MTb = MTf + (size_t)b * 2048 * 8;
#pragma unroll
        for (int rep = 0; rep < 8; rep++) {
            int ch = rep * 256 + tid;
            *(uint4*)&Bs[ch * 8] = *(const uint4*)(MTb + ch * 8);
        }
        __syncthreads();

        // Phase B: out = P(64x64) @ M(64x256)
        float* ob = out + ((size_t)b * NTc + q0 + w * 16 + quad * 4) * Hc + c;
#pragma unroll
        for (int ht = 0; ht < 16; ht++) {
            v8s b0 = *(const v8s*)&Bs[((ht * 2 + 0) * 64 + lane) * 8];
            v8s b1 = *(const v8s*)&Bs[((ht * 2 + 1) * 64 + lane) * 8];
            v4f oc;
            oc[0] = 0.f; oc[1] = 0.f; oc[2] = 0.f; oc[3] = 0.f;
            oc = __builtin_amdgcn_mfma_f32_16x16x32_bf16(pa0, b0, oc, 0, 0, 0);
            oc = __builtin_amdgcn_mfma_f32_16x16x32_bf16(pa1, b1, oc, 0, 0, 0);
#pragma unroll
            for (int rg = 0; rg < 4; rg++)
                ob[(size_t)rg * Hc + ht * 16] = oc[rg];
        }
    }

    grid.sync();   // all Wsum atomics done & visible

    // ================= Phase 2: W expansion =================
    if (bk < 128) {
        int idx = bk * 256 + tid;   // over B*N*T = 32768
        int b = idx >> 10;
        int t = idx & 63;
        Wout[idx] = Wsum[b * Tc + t] * (1.0f / 16.0f);
    }
}

// ---------------------------------------------------------------------------
extern "C" void kernel_launch(void* const* d_in, const int* in_sizes, int n_in,
                              void* d_out, int out_size, void* d_ws, size_t ws_size,
                              hipStream_t stream) {
    const float* node  = (const float*)d_in[0];   // (B,T,H)
    const float* neigh = (const float*)d_in[1];   // (B,N,T,H)
    const int*   nbr   = (const int*)d_in[2];     // (B,) int32/int64 (detected)

    float* out  = (float*)d_out;                  // (B,NT,H) then W (B,N,T)
    float* Wout = out + (size_t)Bc * NTc * Hc;

    u16* NFw = (u16*)d_ws;
    u16* MTw = NFw + NODEF_SZ;
    float* Ww = (float*)(MTw + MTF_SZ);

    void* args[] = {(void*)&neigh, (void*)&node, (void*)&nbr,
                    (void*)&NFw, (void*)&MTw, (void*)&Ww,
                    (void*)&out, (void*)&Wout};
    hipLaunchCooperativeKernel((const void*)mono_kernel,
                               dim3(512), dim3(256), args, 0, stream);
}